// Round 7
// baseline (323.258 us; speedup 1.0000x reference)
//
#include <hip/hip_runtime.h>
#include <hip/hip_bf16.h>

typedef __attribute__((ext_vector_type(4))) float  f32x4;
typedef __attribute__((ext_vector_type(8))) __bf16 bf16x8;
typedef __attribute__((ext_vector_type(8))) short  short8;

#define KDIM 4096
#define NDIM 4096
#define BK   32
#define NT   (KDIM / BK)     // 128 K-tiles

__device__ inline unsigned short f2bf(float f) {
    union { float f; unsigned u; } v; v.f = f;
    unsigned r = v.u + 0x7fffu + ((v.u >> 16) & 1u);   // RNE
    return (unsigned short)(r >> 16);
}

// ---------- kernel 1: dequant weight codes -> bf16 [N][K] ----------
__global__ void dequant_w(const int* __restrict__ wq, const float* __restrict__ absmax,
                          const float* __restrict__ code, short* __restrict__ wout) {
    __shared__ float cs[256];
    cs[threadIdx.x] = code[threadIdx.x];
    __syncthreads();
    size_t idx = ((size_t)blockIdx.x * blockDim.x + threadIdx.x) * 8;
    float am = absmax[idx >> 12];                      // BLOCKSIZE = 4096
    int4 q0 = *(const int4*)(wq + idx);
    int4 q1 = *(const int4*)(wq + idx + 4);
    short8 r;
    r[0] = (short)f2bf(cs[q0.x] * am);
    r[1] = (short)f2bf(cs[q0.y] * am);
    r[2] = (short)f2bf(cs[q0.z] * am);
    r[3] = (short)f2bf(cs[q0.w] * am);
    r[4] = (short)f2bf(cs[q1.x] * am);
    r[5] = (short)f2bf(cs[q1.y] * am);
    r[6] = (short)f2bf(cs[q1.z] * am);
    r[7] = (short)f2bf(cs[q1.w] * am);
    *(short8*)(wout + idx) = r;
}

// ---------- kernel 2: x fp32 -> bf16 [M][K] ----------
__global__ void cvt_x(const float* __restrict__ xin, short* __restrict__ xout) {
    size_t idx = ((size_t)blockIdx.x * blockDim.x + threadIdx.x) * 8;
    float4 a = *(const float4*)(xin + idx);
    float4 b = *(const float4*)(xin + idx + 4);
    short8 r;
    r[0] = (short)f2bf(a.x); r[1] = (short)f2bf(a.y);
    r[2] = (short)f2bf(a.z); r[3] = (short)f2bf(a.w);
    r[4] = (short)f2bf(b.x); r[5] = (short)f2bf(b.y);
    r[6] = (short)f2bf(b.z); r[7] = (short)f2bf(b.w);
    *(short8*)(xout + idx) = r;
}

// ---------- kernel 3: 128x256 bf16 NT GEMM, BK=32, 2 blocks/CU ----------
// C = A[M,K] * B[N,K]^T + bias.  8 waves (2 row-halves x 4 col-quarters),
// per-wave 64x64 output via 16x mfma_f32_16x16x32_bf16 per K-tile.
// LDS: 2 bufs x (A[128][32] + B[256][32]) bf16 = 48 KiB -> 2+ blocks/CU;
// cross-block wave overlap hides the per-block LDS-read/MFMA serialization.
// Swizzle for 64-B rows: S(a) = ((a>>7)&3)<<4 (involution; beat-level
// bank walk verified conflict-free).  Linear global_load_lds dest +
// pre-swizzled global source; ds_read at a ^ S(a)  (both-sides rule).
// Schedule: T3 minimum 2-phase — {STAGE(t+1) | RD(t)} -> lgkm0 -> MFMA
// -> vmcnt0 -> BAR; one barrier per K-tile.
__global__ __launch_bounds__(512, 4) void gemm128x256(
    const short* __restrict__ A, const short* __restrict__ Bm,
    const float* __restrict__ bias, float* __restrict__ C, int M) {

    __shared__ __attribute__((aligned(128))) char lds[49152];

    const int tid  = threadIdx.x;
    const int wid  = tid >> 6;
    const int lane = tid & 63;
    const int wr   = wid >> 2;        // 0..1 : 64-row half
    const int wc   = wid & 3;         // 0..3 : 64-col quarter
    const int lr   = lane & 15;
    const int kl2  = (lane >> 4) * 16;   // kl*2 bytes (k fragment offset)

    // XCD-aware chunked swizzle (1024 wg, %8==0 -> bijective)
    const int nwg  = gridDim.x;
    const int cpx  = nwg >> 3;
    const int swzb = (blockIdx.x & 7) * cpx + (blockIdx.x >> 3);
    const int bx   = swzb & 15;              // N/256 = 16 tiles, fastest (A-panel reuse)
    const int by   = swzb >> 4;              // M/128 = 64
    const int tileM = by * 128, tileN = bx * 256;

    // ---- read-side swizzle: (row>>1)&3 == (lr>>1)&3 for A and B fragments
    const int kb = kl2 ^ (((lr >> 1) & 3) << 4);

    // ---- staging: linear LDS dest (tid*16), source pre-XORed with S
    const int u  = (tid * 16) ^ (((tid >> 3) & 3) << 4);
    const int sr = u >> 6;                   // row 0..127
    const int sc = (u & 63) >> 1;            // col element 0..31

    const short* pa  = A  + (size_t)(tileM + sr) * KDIM + sc;
    const short* pb0 = Bm + (size_t)(tileN + sr) * KDIM + sc;
    const short* pb1 = Bm + (size_t)(tileN + 128 + sr) * KDIM + sc;

#define GL(SRC, DST) __builtin_amdgcn_global_load_lds(                         \
    (const __attribute__((address_space(1))) void*)(SRC),                      \
    (__attribute__((address_space(3))) void*)(DST), 16, 0, 0)

    // stage K-tile at element offset KT into buffer B_ (3 gloads/thread)
#define STG(B_, KT) do {                                                       \
    char* _d = lds + (B_) * 24576 + tid * 16;                                  \
    GL(pa  + (KT), _d);                                                        \
    GL(pb0 + (KT), _d + 8192);                                                 \
    GL(pb1 + (KT), _d + 16384);                                                \
} while (0)

    f32x4  acc[4][4] = {};
    bf16x8 aF[4], bF[4];

#define RD(B_) do {                                                            \
    const char* _ra = lds + (B_) * 24576 + (wr * 64 + lr) * 64 + kb;           \
    _Pragma("unroll") for (int mi = 0; mi < 4; ++mi)                           \
        aF[mi] = *(const bf16x8*)(_ra + mi * 1024);                            \
    const char* _rb = lds + (B_) * 24576 + 8192 + (wc * 64 + lr) * 64 + kb;    \
    _Pragma("unroll") for (int ni = 0; ni < 4; ++ni)                           \
        bF[ni] = *(const bf16x8*)(_rb + ni * 1024);                            \
} while (0)

#define MM() do {                                                              \
    __builtin_amdgcn_s_setprio(1);                                             \
    _Pragma("unroll") for (int mi = 0; mi < 4; ++mi)                           \
    _Pragma("unroll") for (int ni = 0; ni < 4; ++ni)                           \
        acc[mi][ni] = __builtin_amdgcn_mfma_f32_16x16x32_bf16(                 \
            aF[mi], bF[ni], acc[mi][ni], 0, 0, 0);                             \
    __builtin_amdgcn_s_setprio(0);                                             \
} while (0)

#define BAR()       __builtin_amdgcn_s_barrier()
#define WAIT_LGKM() do { asm volatile("s_waitcnt lgkmcnt(0)" ::: "memory");    \
                         __builtin_amdgcn_sched_barrier(0); } while (0)
#define WAIT_VM0()  asm volatile("s_waitcnt vmcnt(0)" ::: "memory")

    // ---- prologue: stage tile 0 into buf0
    STG(0, 0);
    WAIT_VM0();
    BAR();

    // ---- main loop: 128 tiles, unrolled x2 for static buffer parity
    for (int it = 0; it < NT / 2; ++it) {
        const int t = 2 * it;
        STG(1, ((t + 1) * BK) & (KDIM - 1));   // stage t+1 -> buf1
        RD(0);                                 // read tile t from buf0
        WAIT_LGKM();
        MM();
        WAIT_VM0();                            // t+1 fully in LDS
        BAR();

        STG(0, ((t + 2) * BK) & (KDIM - 1));   // stage t+2 -> buf0 (t=126 wraps, harmless)
        RD(1);                                 // read tile t+1 from buf1
        WAIT_LGKM();
        MM();
        WAIT_VM0();
        BAR();
    }

    // ---- epilogue: C/D layout col = lane&15, row = (lane>>4)*4 + reg
    const int r4 = (lane >> 4) * 4;
    float bv[4];
    #pragma unroll
    for (int ni = 0; ni < 4; ++ni)
        bv[ni] = bias[tileN + wc * 64 + ni * 16 + lr];

    #pragma unroll
    for (int mi = 0; mi < 4; ++mi)
    #pragma unroll
    for (int ni = 0; ni < 4; ++ni) {
        const int row0 = tileM + wr * 64 + mi * 16 + r4;
        const int col  = tileN + wc * 64 + ni * 16 + lr;
        f32x4 v = acc[mi][ni];
        #pragma unroll
        for (int j = 0; j < 4; ++j)
            C[(size_t)(row0 + j) * NDIM + col] = v[j] + bv[ni];
    }
}

extern "C" void kernel_launch(void* const* d_in, const int* in_sizes, int n_in,
                              void* d_out, int out_size, void* d_ws, size_t ws_size,
                              hipStream_t stream) {
    const float* x      = (const float*)d_in[0];
    const int*   wq     = (const int*)  d_in[1];
    const float* absmax = (const float*)d_in[2];
    const float* code   = (const float*)d_in[3];
    const float* bias   = (const float*)d_in[4];
    float* out = (float*)d_out;

    const int K = KDIM, N = NDIM;
    const int M = in_sizes[0] / K;            // 8192

    short* wbf = (short*)d_ws;                // [N][K] bf16: 32 MiB
    short* xbf = wbf + (size_t)N * K;         // [M][K] bf16: 64 MiB

    dequant_w<<<(size_t)N * K / 8 / 256, 256, 0, stream>>>(wq, absmax, code, wbf);
    cvt_x    <<<(size_t)M * K / 8 / 256, 256, 0, stream>>>(x, xbf);

    const int nwg = (M / 128) * (N / 256);    // 1024, %8 == 0
    gemm128x256<<<nwg, 512, 0, stream>>>(xbf, wbf, bias, out, M);
}

// Round 8
// 269.886 us; speedup vs baseline: 1.1978x; 1.1978x over previous
//
#include <hip/hip_runtime.h>
#include <hip/hip_bf16.h>

typedef __attribute__((ext_vector_type(4))) float  f32x4;
typedef __attribute__((ext_vector_type(8))) __bf16 bf16x8;
typedef __attribute__((ext_vector_type(8))) short  short8;

#define KDIM 4096
#define NDIM 4096
#define BK   64
#define NT   (KDIM / BK)     // 64 K-tiles

__device__ inline unsigned short f2bf(float f) {
    union { float f; unsigned u; } v; v.f = f;
    unsigned r = v.u + 0x7fffu + ((v.u >> 16) & 1u);   // RNE
    return (unsigned short)(r >> 16);
}

// ---------- kernel 1: dequant weight codes -> bf16 [N][K] ----------
__global__ void dequant_w(const int* __restrict__ wq, const float* __restrict__ absmax,
                          const float* __restrict__ code, short* __restrict__ wout) {
    __shared__ float cs[256];
    cs[threadIdx.x] = code[threadIdx.x];
    __syncthreads();
    size_t idx = ((size_t)blockIdx.x * blockDim.x + threadIdx.x) * 8;
    float am = absmax[idx >> 12];                      // BLOCKSIZE = 4096
    int4 q0 = *(const int4*)(wq + idx);
    int4 q1 = *(const int4*)(wq + idx + 4);
    short8 r;
    r[0] = (short)f2bf(cs[q0.x] * am);
    r[1] = (short)f2bf(cs[q0.y] * am);
    r[2] = (short)f2bf(cs[q0.z] * am);
    r[3] = (short)f2bf(cs[q0.w] * am);
    r[4] = (short)f2bf(cs[q1.x] * am);
    r[5] = (short)f2bf(cs[q1.y] * am);
    r[6] = (short)f2bf(cs[q1.z] * am);
    r[7] = (short)f2bf(cs[q1.w] * am);
    *(short8*)(wout + idx) = r;
}

// ---------- kernel 2: x fp32 -> bf16 [M][K] ----------
__global__ void cvt_x(const float* __restrict__ xin, short* __restrict__ xout) {
    size_t idx = ((size_t)blockIdx.x * blockDim.x + threadIdx.x) * 8;
    float4 a = *(const float4*)(xin + idx);
    float4 b = *(const float4*)(xin + idx + 4);
    short8 r;
    r[0] = (short)f2bf(a.x); r[1] = (short)f2bf(a.y);
    r[2] = (short)f2bf(a.z); r[3] = (short)f2bf(a.w);
    r[4] = (short)f2bf(b.x); r[5] = (short)f2bf(b.y);
    r[6] = (short)f2bf(b.z); r[7] = (short)f2bf(b.w);
    *(short8*)(xout + idx) = r;
}

// ---------- kernel 3: 256x256 2-phase bf16 NT GEMM, compiler-counted lgkm ----------
// R6 structure with the mid-phase barrier and the lgkmcnt(0)+sched_barrier
// fence REMOVED: ds_reads and MFMAs are compiler-scheduled so the first
// MFMAs overlap the tail of the LDS read burst (counted lgkmcnt waits).
// PhA(t): {16 ds_read | stage B-lo(t+1),A-hi(t+1)} -> 32 MFMA -> bar
// PhB(t): {8 ds_read  | stage A-lo(t+2),B-hi(t+2)} -> 32 MFMA -> vmcnt(4) -> bar
// Slot lifetimes / vmcnt accounting identical to R6 (verified sound).
// Swizzle S(a) = ((a>>7)&7)<<4 (R3-verified, 0 conflicts).
__global__ __launch_bounds__(512, 2) void gemm256(
    const short* __restrict__ A, const short* __restrict__ Bm,
    const float* __restrict__ bias, float* __restrict__ C, int M) {

    __shared__ __attribute__((aligned(128))) char lds[131072];

    const int tid  = threadIdx.x;
    const int wid  = tid >> 6;
    const int lane = tid & 63;
    const int wr   = wid >> 2;        // 0..1 : 64-row piece within quadrant
    const int wc   = wid & 3;         // 0..3 : 32-col piece within quadrant
    const int lr   = lane & 15;
    const int kl   = (lane >> 4) * 8; // k element offset of fragment

    // XCD-aware chunked swizzle (512 wg, %8==0 -> bijective)
    const int nwg  = gridDim.x;
    const int cpx  = nwg >> 3;
    const int swzb = (blockIdx.x & 7) * cpx + (blockIdx.x >> 3);
    const int bx   = swzb & 15;              // NDIM/256 = 16 tiles, fastest
    const int by   = swzb >> 4;
    const int tileM = by * 256, tileN = bx * 256;

    // ---- read-side swizzle: row&7 == lr&7 for both A and B fragments
    const int swb = (lr & 7) << 4;
    const int kb0 = (kl * 2) ^ swb;
    const int kb1 = (kl * 2 + 64) ^ swb;
    const int arow = (wr * 64 + lr) * 128;   // region-relative byte row base
    const int brow = (wc * 32 + lr) * 128;

    // ---- staging: linear LDS dest (tid*16), source pre-XORed with S
    const int u0 = (tid * 16) ^ (((tid >> 3) & 7) << 4);
    const int u1 = (8192 + tid * 16) ^ (((tid >> 3) & 7) << 4);
    const int srow0 = u0 >> 7, scol0 = (u0 & 127) >> 1;   // rows 0..63
    const int srow1 = u1 >> 7, scol1 = (u1 & 127) >> 1;   // rows 64..127

    const short* pA0 = A  + (size_t)(tileM + srow0) * KDIM + scol0;
    const short* pA1 = A  + (size_t)(tileM + srow1) * KDIM + scol1;
    const short* pB0 = Bm + (size_t)(tileN + srow0) * KDIM + scol0;
    const short* pB1 = Bm + (size_t)(tileN + srow1) * KDIM + scol1;

#define LDSA(b) (lds + (b) * 65536)
#define LDSB(b) (lds + (b) * 65536 + 32768)

#define STAGE(PM0, PM1, REG, H, KS) do {                                       \
    char* _l = (REG) + (H) * 16384 + wid * 1024;                               \
    __builtin_amdgcn_global_load_lds(                                          \
        (const __attribute__((address_space(1))) void*)((PM0) + (size_t)(H) * 128 * KDIM + (KS)), \
        (__attribute__((address_space(3))) void*)(_l), 16, 0, 0);              \
    __builtin_amdgcn_global_load_lds(                                          \
        (const __attribute__((address_space(1))) void*)((PM1) + (size_t)(H) * 128 * KDIM + (KS)), \
        (__attribute__((address_space(3))) void*)(_l + 8192), 16, 0, 0);       \
} while (0)

    f32x4  acc[2][2][4][2] = {};   // [qr][qc][mi][ni]
    bf16x8 aF[4][2];               // [mi][ks]  (current QR)
    bf16x8 bF0[2][2], bF1[2][2];   // [ni][ks]  (QC=0 and QC=1, both kept live)

#define RDA(b, QR) do {                                                        \
    _Pragma("unroll") for (int mi = 0; mi < 4; ++mi) {                         \
        const char* _p = LDSA(b) + (QR) * 16384 + mi * 2048 + arow;            \
        aF[mi][0] = *(const bf16x8*)(_p + kb0);                                \
        aF[mi][1] = *(const bf16x8*)(_p + kb1);                                \
    } } while (0)

#define RDB(b, QC, DST) do {                                                   \
    _Pragma("unroll") for (int ni = 0; ni < 2; ++ni) {                         \
        const char* _p = LDSB(b) + (QC) * 16384 + ni * 2048 + brow;            \
        DST[ni][0] = *(const bf16x8*)(_p + kb0);                               \
        DST[ni][1] = *(const bf16x8*)(_p + kb1);                               \
    } } while (0)

    // 32 MFMA: both column-quadrants of row-quadrant QR.
    // NO manual lgkm fence: compiler inserts counted lgkmcnt waits so the
    // first MFMAs overlap the tail of the ds_read burst.
#define MFMA32(QR) do {                                                        \
    __builtin_amdgcn_s_setprio(1);                                             \
    _Pragma("unroll") for (int ks = 0; ks < 2; ++ks)                           \
    _Pragma("unroll") for (int mi = 0; mi < 4; ++mi) {                         \
        _Pragma("unroll") for (int ni = 0; ni < 2; ++ni)                       \
            acc[QR][0][mi][ni] = __builtin_amdgcn_mfma_f32_16x16x32_bf16(      \
                aF[mi][ks], bF0[ni][ks], acc[QR][0][mi][ni], 0, 0, 0);         \
        _Pragma("unroll") for (int ni = 0; ni < 2; ++ni)                       \
            acc[QR][1][mi][ni] = __builtin_amdgcn_mfma_f32_16x16x32_bf16(      \
                aF[mi][ks], bF1[ni][ks], acc[QR][1][mi][ni], 0, 0, 0);         \
    }                                                                          \
    __builtin_amdgcn_s_setprio(0);                                             \
} while (0)

#define BAR() __builtin_amdgcn_s_barrier()

    // PhA(t), buf b: reads A-lo,B-lo,B-hi; stages B-lo(t+1),A-hi(t+1) -> buf ~b
#define PHA(b, KS, DO_ST) do {                                                 \
    RDA(b, 0); RDB(b, 0, bF0); RDB(b, 1, bF1);                                 \
    if (DO_ST) {                                                               \
        STAGE(pB0, pB1, LDSB(1 - (b)), 0, KS);                                 \
        STAGE(pA0, pA1, LDSA(1 - (b)), 1, KS);                                 \
    }                                                                          \
    MFMA32(0); BAR();                                                          \
} while (0)

    // PhB(t), buf b: reads A-hi; stages A-lo(t+2),B-hi(t+2) -> buf b
#define PHB(b, KS, DO_ST, VMN) do {                                            \
    RDA(b, 1);                                                                 \
    if (DO_ST) {                                                               \
        STAGE(pA0, pA1, LDSA(b), 0, KS);                                       \
        STAGE(pB0, pB1, LDSB(b), 1, KS);                                       \
    }                                                                          \
    MFMA32(1);                                                                 \
    if ((VMN) == 4)      asm volatile("s_waitcnt vmcnt(4)" ::: "memory");      \
    else if ((VMN) == 0) asm volatile("s_waitcnt vmcnt(0)" ::: "memory");      \
    BAR();                                                                     \
} while (0)

    // ---- prologue: tile0 all 4 halves + tile1 {A-lo, B-hi}  (= PhB(-1))
    STAGE(pA0, pA1, LDSA(0), 0, 0);
    STAGE(pA0, pA1, LDSA(0), 1, 0);
    STAGE(pB0, pB1, LDSB(0), 0, 0);
    STAGE(pB0, pB1, LDSB(0), 1, 0);
    STAGE(pA0, pA1, LDSA(1), 0, BK);
    STAGE(pB0, pB1, LDSB(1), 1, BK);
    asm volatile("s_waitcnt vmcnt(4)" ::: "memory");   // tile0 landed
    BAR();

    // ---- main loop: tiles 0..61 (31 iterations x 2 tiles)
    for (int it = 0; it < NT / 2 - 1; ++it) {
        const int k1 = ((2 * it + 1) * BK) & (KDIM - 1);
        const int k2 = ((2 * it + 2) * BK) & (KDIM - 1);
        const int k3 = ((2 * it + 3) * BK) & (KDIM - 1);
        PHA(0, k1, 1);          // t=2it:   stage B-lo/A-hi(t+1)
        PHB(0, k2, 1, 4);       //          stage A-lo/B-hi(t+2)
        PHA(1, k2, 1);          // t=2it+1: stage B-lo/A-hi(t+2)
        PHB(1, k3, 1, 4);       //          stage A-lo/B-hi(t+3)
    }
    // ---- tail: tiles 62, 63
    {
        const int k1 = ((NT - 1) * BK) & (KDIM - 1);   // tile 63 offset
        PHA(0, k1, 1);          // t=62: stage B-lo/A-hi(63)
        PHB(0, 0, 0, 0);        //       drain all staging
        PHA(1, 0, 0);           // t=63
        PHB(1, 0, 0, -1);
    }

    // ---- epilogue: C/D layout col = lane&15, row = (lane>>4)*4 + reg
    const int r4 = (lane >> 4) * 4;
    float bv[2][2];
    #pragma unroll
    for (int qc = 0; qc < 2; ++qc)
        #pragma unroll
        for (int ni = 0; ni < 2; ++ni)
            bv[qc][ni] = bias[tileN + qc * 128 + wc * 32 + ni * 16 + lr];

    #pragma unroll
    for (int qr = 0; qr < 2; ++qr)
    #pragma unroll
    for (int qc = 0; qc < 2; ++qc)
    #pragma unroll
    for (int mi = 0; mi < 4; ++mi)
    #pragma unroll
    for (int ni = 0; ni < 2; ++ni) {
        const int row0 = tileM + qr * 128 + wr * 64 + mi * 16 + r4;
        const int col  = tileN + qc * 128 + wc * 32 + ni * 16 + lr;
        f32x4 v = acc[qr][qc][mi][ni];
        #pragma unroll
        for (int j = 0; j < 4; ++j)
            C[(size_t)(row0 + j) * NDIM + col] = v[j] + bv[qc][ni];
    }
}

extern "C" void kernel_launch(void* const* d_in, const int* in_sizes, int n_in,
                              void* d_out, int out_size, void* d_ws, size_t ws_size,
                              hipStream_t stream) {
    const float* x      = (const float*)d_in[0];
    const int*   wq     = (const int*)  d_in[1];
    const float* absmax = (const float*)d_in[2];
    const float* code   = (const float*)d_in[3];
    const float* bias   = (const float*)d_in[4];
    float* out = (float*)d_out;

    const int K = KDIM, N = NDIM;
    const int M = in_sizes[0] / K;            // 8192

    short* wbf = (short*)d_ws;                // [N][K] bf16: 32 MiB
    short* xbf = wbf + (size_t)N * K;         // [M][K] bf16: 64 MiB

    dequant_w<<<(size_t)N * K / 8 / 256, 256, 0, stream>>>(wq, absmax, code, wbf);
    cvt_x    <<<(size_t)M * K / 8 / 256, 256, 0, stream>>>(x, xbf);

    const int nwg = (M / 256) * (N / 256);    // 512, %8 == 0
    gemm256<<<nwg, 512, 0, stream>>>(xbf, wbf, bias, out, M);
}